// Round 1
// 187.875 us; speedup vs baseline: 1.0514x; 1.0514x over previous
//
#include <hip/hip_runtime.h>
#include <hip/hip_bf16.h>
#include <math.h>

#define B_   128
#define T_   256
#define C_   384
#define H_   6
#define HS_  64
#define NTOK (B_*T_)          // 32768
#define NQKV (3*C_)           // 1152

typedef unsigned short u16;
typedef __attribute__((ext_vector_type(8))) short bf16x8;   // 8 bf16 in 4 VGPRs
typedef __attribute__((ext_vector_type(4))) float f32x4;

__device__ __forceinline__ u16 f2b(float f) {
    unsigned int u = __builtin_bit_cast(unsigned int, f);
    unsigned int r = (u + 0x7FFFu + ((u >> 16) & 1u)) >> 16;   // RNE
    return (u16)r;
}

__device__ __forceinline__ float fexp2(float x) {
#if __has_builtin(__builtin_amdgcn_exp2f)
    return __builtin_amdgcn_exp2f(x);
#else
    return exp2f(x);
#endif
}

// async global->LDS, 16B per lane.  LDS dst = wave-uniform base + lane*16B.
__device__ __forceinline__ void gl2lds16(const u16* g, u16* l) {
    __builtin_amdgcn_global_load_lds(
        (const __attribute__((address_space(1))) unsigned int*)g,
        (__attribute__((address_space(3))) unsigned int*)l, 16, 0, 0);
}

// log2(e) * (1/sqrt(64)) folded into q at the qkv epilogue; attn uses exp2.
#define QSCALE 0.180336880f

// ---------------------------------------------------------------------------
// Fused prep: x->bf16 (8/thread), Wp->bf16 (8/thread), Wcat_t build (1/thread)
// wct layout is now HEAD-MAJOR: row n2 = h*192 + p*64 + d  (p in {q,k,v}),
// so the fused kernel stages one head's 192 weight rows contiguously.
// ---------------------------------------------------------------------------
#define J0_ (NTOK*C_/8)     // 1,572,864
#define J2_ (C_*C_/8)       // 18,432
#define J1_ (NQKV*C_)       // 442,368

__global__ __launch_bounds__(256) void prep(
    const float* __restrict__ x,  const float* __restrict__ Wq,
    const float* __restrict__ Wk, const float* __restrict__ Wv,
    const float* __restrict__ Wp,
    u16* __restrict__ xb, u16* __restrict__ wct, u16* __restrict__ wpb)
{
    int i = blockIdx.x * 256 + threadIdx.x;
    if (i < J0_) {
        const float4* s = (const float4*)x + (size_t)i * 2;
        float4 a = s[0], b = s[1];
        ushort4 o1, o2;
        o1.x = f2b(a.x); o1.y = f2b(a.y); o1.z = f2b(a.z); o1.w = f2b(a.w);
        o2.x = f2b(b.x); o2.y = f2b(b.y); o2.z = f2b(b.z); o2.w = f2b(b.w);
        ((ushort4*)xb)[(size_t)i * 2]     = o1;
        ((ushort4*)xb)[(size_t)i * 2 + 1] = o2;
    } else if (i < J0_ + J2_) {
        int j = i - J0_;
        const float4* s = (const float4*)Wp + (size_t)j * 2;
        float4 a = s[0], b = s[1];
        ushort4 o1, o2;
        o1.x = f2b(a.x); o1.y = f2b(a.y); o1.z = f2b(a.z); o1.w = f2b(a.w);
        o2.x = f2b(b.x); o2.y = f2b(b.y); o2.z = f2b(b.z); o2.w = f2b(b.w);
        ((ushort4*)wpb)[(size_t)j * 2]     = o1;
        ((ushort4*)wpb)[(size_t)j * 2 + 1] = o2;
    } else {
        int j = i - J0_ - J2_;
        if (j < J1_) {
            int n = j / C_, c = j % C_;
            int h = n / 192, rem = n % 192;       // head-major rows
            int p = rem >> 6, d = rem & 63;
            const float* W = (p == 0 ? Wq : (p == 1 ? Wk : Wv));
            wct[j] = f2b(W[(h * C_ + c) * HS_ + d]);
        }
    }
}

// ---------------------------------------------------------------------------
// Fused QKV projection + causal flash attention.  One block per (b,h).
// Phase 1: GEMM x[b](256x384) @ Wcat[h]^T(384x192) -> acc, 8 waves 4Mx2N.
//          Staging aliases the Q/K/V LDS regions (dead until epilogue).
// Phase 2: acc -> LDS:  Q[256][64] row-swizzled (scaled by QSCALE),
//          K[256][64] row-swizzled, V^T[64][256] chunk-swizzled.
// Phase 3: causal attention entirely from LDS (no global traffic),
//          wave w owns rows {w*16, 128+w*16} (+15) for causal balance.
// Phase 4: 1/l rescale + LDS transpose + 16B coalesced yb stores.
// LDS 96 KB -> 1 block/CU (8 waves).  XCD-affine: 6 heads of b share an XCD
// so x[b] (192 KB bf16) is L2-resident after the first head.
// ---------------------------------------------------------------------------
__global__ __launch_bounds__(512, 2) void qkv_attn(
    const u16* __restrict__ xb, const u16* __restrict__ wct,
    u16* __restrict__ yb)
{
    __shared__ __align__(16) u16 SM[49152];       // 96 KB
    u16* Qs = SM;                 // [256][64] swz   (aliases X-stage, P-scratch)
    u16* Ks = SM + 16384;         // [256][64] swz   (aliases W-stage)
    u16* Vs = SM + 32768;         // [64][256] V^T swz

    const int gid = blockIdx.x;                    // 768 = 8 XCD * 96
    const int lin = (gid & 7) * 96 + (gid >> 3);   // bijective XCD swizzle
    const int b = lin / 6, h = lin % 6;

    const int tid = threadIdx.x;
    const int w = tid >> 6, lane = tid & 63;
    const int lm = lane & 15, qd = lane >> 4;
    const int wm = (w >> 1) * 64, wn = (w & 1) * 96;   // GEMM wave tile 64x96

    // ---- Phase 1: QKV GEMM ------------------------------------------------
    const int schunk = (lane & 7) ^ ((lane >> 3) & 7);   // XOR store swizzle
    const u16* gA = xb  + (size_t)(b * T_ + w * 32 + (lane >> 3)) * C_ + schunk * 8;
    const u16* gB = wct + (size_t)(h * 192 + w * 24 + (lane >> 3)) * C_ + schunk * 8;
    u16* lA = &Qs[(w * 32) * 64];
    u16* lB = &Ks[(w * 24) * 64];

    f32x4 acc[4][6];
    #pragma unroll
    for (int mi = 0; mi < 4; ++mi)
        #pragma unroll
        for (int ni = 0; ni < 6; ++ni)
            acc[mi][ni] = (f32x4){0.f, 0.f, 0.f, 0.f};

    for (int k0 = 0; k0 < C_; k0 += 64) {
        __syncthreads();
        #pragma unroll
        for (int j = 0; j < 4; ++j)                 // X tile: 256x64 bf16
            gl2lds16(gA + j * 8 * C_, lA + j * 8 * 64);
        #pragma unroll
        for (int j = 0; j < 3; ++j)                 // W tile: 192x64 bf16
            gl2lds16(gB + j * 8 * C_, lB + j * 8 * 64);
        gA += 64; gB += 64;
        __syncthreads();

        #pragma unroll
        for (int ks = 0; ks < 2; ++ks) {
            bf16x8 af[4], bfr[6];
            #pragma unroll
            for (int mi = 0; mi < 4; ++mi) {
                const int row = wm + mi * 16 + lm;
                const int sl = (ks * 4 + qd) ^ (lm & 7);
                af[mi] = *(const bf16x8*)&Qs[row * 64 + sl * 8];
            }
            #pragma unroll
            for (int ni = 0; ni < 6; ++ni) {
                const int row = wn + ni * 16 + lm;
                const int sl = (ks * 4 + qd) ^ (lm & 7);
                bfr[ni] = *(const bf16x8*)&Ks[row * 64 + sl * 8];
            }
            #pragma unroll
            for (int mi = 0; mi < 4; ++mi)
                #pragma unroll
                for (int ni = 0; ni < 6; ++ni)
                    acc[mi][ni] = __builtin_amdgcn_mfma_f32_16x16x32_bf16(
                        af[mi], bfr[ni], acc[mi][ni], 0, 0, 0);
        }
    }

    // ---- Phase 2: acc -> Q/K/V in LDS -------------------------------------
    __syncthreads();     // all stage-buffer reads drained; regions reusable
    #pragma unroll
    for (int mi = 0; mi < 4; ++mi) {
        const int t0 = wm + mi * 16 + qd * 4;
        #pragma unroll
        for (int ni = 0; ni < 6; ++ni) {
            const int n = wn + ni * 16 + lm;      // category uniform per (w,ni)
            if (n < 64) {                         // Q, scaled, row-swizzled
                #pragma unroll
                for (int r = 0; r < 4; ++r) {
                    const int t = t0 + r;
                    Qs[t * 64 + (((n >> 3) ^ (t & 7)) << 3) + (n & 7)]
                        = f2b(acc[mi][ni][r] * QSCALE);
                }
            } else if (n < 128) {                 // K, row-swizzled
                const int d = n - 64;
                #pragma unroll
                for (int r = 0; r < 4; ++r) {
                    const int t = t0 + r;
                    Ks[t * 64 + (((d >> 3) ^ (t & 7)) << 3) + (d & 7)]
                        = f2b(acc[mi][ni][r]);
                }
            } else {                              // V -> V^T[d][t], 8B packed
                const int d = n - 128;
                const int ch = t0 >> 3;           // t0 % 8 in {0,4}
                const int pos = (ch & 16) | ((ch ^ (d & 15)) & 15);
                ushort4 sv;
                sv.x = f2b(acc[mi][ni][0]); sv.y = f2b(acc[mi][ni][1]);
                sv.z = f2b(acc[mi][ni][2]); sv.w = f2b(acc[mi][ni][3]);
                *(ushort4*)&Vs[d * 256 + pos * 8 + (t0 & 7)] = sv;
            }
        }
    }
    __syncthreads();

    // Q fragments to registers: wave w owns rows rg*128 + w*16 .. +15
    bf16x8 aq[2][2];
    #pragma unroll
    for (int rg = 0; rg < 2; ++rg) {
        const int t = rg * 128 + w * 16 + lm;
        #pragma unroll
        for (int ks = 0; ks < 2; ++ks)
            aq[rg][ks] = *(const bf16x8*)
                &Qs[t * 64 + (((ks * 4 + qd) ^ (t & 7)) << 3)];
    }
    __syncthreads();     // Qs region now reusable as per-wave P scratch

    // ---- Phase 3: causal attention, all K/V in LDS ------------------------
    f32x4 oacc[2][4];
    float ms[2][4], ls[2][4];
    #pragma unroll
    for (int rg = 0; rg < 2; ++rg) {
        #pragma unroll
        for (int ni = 0; ni < 4; ++ni) oacc[rg][ni] = (f32x4){0.f, 0.f, 0.f, 0.f};
        #pragma unroll
        for (int r = 0; r < 4; ++r) { ms[rg][r] = -INFINITY; ls[rg][r] = 0.f; }
    }

    u16* Pw = SM + w * (16 * 72);    // per-wave, in-order DS pipe, no barrier

    #pragma unroll
    for (int rg = 0; rg < 2; ++rg) {
        const int trg = rg * 128 + w * 16;
        const int kmax = (trg + 15) >> 6;
        for (int kt = 0; kt <= kmax; ++kt) {
            const int j0 = kt * 64;
            const bool needmask = (j0 + 63 > trg);

            // S = Q K^T  (16 x 64)
            f32x4 st[4];
            #pragma unroll
            for (int ni = 0; ni < 4; ++ni) st[ni] = (f32x4){0.f, 0.f, 0.f, 0.f};
            #pragma unroll
            for (int ks = 0; ks < 2; ++ks) {
                #pragma unroll
                for (int ni = 0; ni < 4; ++ni) {
                    const int krow = j0 + ni * 16 + lm;
                    const int sl = (ks * 4 + qd) ^ (lm & 7);
                    bf16x8 bk = *(const bf16x8*)&Ks[krow * 64 + sl * 8];
                    st[ni] = __builtin_amdgcn_mfma_f32_16x16x32_bf16(
                        aq[rg][ks], bk, st[ni], 0, 0, 0);
                }
            }

            // online softmax (base-2; q pre-scaled by log2e/8)
            float vals[4][4], rowmax[4];
            #pragma unroll
            for (int r = 0; r < 4; ++r) rowmax[r] = -INFINITY;
            #pragma unroll
            for (int ni = 0; ni < 4; ++ni) {
                const int s_g = j0 + ni * 16 + lm;
                #pragma unroll
                for (int r = 0; r < 4; ++r) {
                    float sc = st[ni][r];
                    if (needmask) {
                        const int t_g = trg + qd * 4 + r;
                        sc = (s_g > t_g) ? -1e30f : sc;
                    }
                    vals[ni][r] = sc;
                    rowmax[r] = fmaxf(rowmax[r], sc);
                }
            }
            #pragma unroll
            for (int msk = 1; msk <= 8; msk <<= 1)
                #pragma unroll
                for (int r = 0; r < 4; ++r)
                    rowmax[r] = fmaxf(rowmax[r], __shfl_xor(rowmax[r], msk, 64));

            float corr[4], rowsum[4];
            #pragma unroll
            for (int r = 0; r < 4; ++r) {
                const float mn = fmaxf(ms[rg][r], rowmax[r]);
                corr[r] = fexp2(ms[rg][r] - mn);
                ms[rg][r] = mn;
                rowsum[r] = 0.f;
            }
            #pragma unroll
            for (int ni = 0; ni < 4; ++ni) {
                #pragma unroll
                for (int r = 0; r < 4; ++r) {
                    const float pv = fexp2(vals[ni][r] - ms[rg][r]);
                    rowsum[r] += pv;
                    Pw[(qd * 4 + r) * 72 + ni * 16 + lm] = f2b(pv);
                }
            }
            #pragma unroll
            for (int msk = 1; msk <= 8; msk <<= 1)
                #pragma unroll
                for (int r = 0; r < 4; ++r)
                    rowsum[r] += __shfl_xor(rowsum[r], msk, 64);
            #pragma unroll
            for (int r = 0; r < 4; ++r) ls[rg][r] = ls[rg][r] * corr[r] + rowsum[r];
            #pragma unroll
            for (int ni = 0; ni < 4; ++ni)
                #pragma unroll
                for (int r = 0; r < 4; ++r)
                    oacc[rg][ni][r] *= corr[r];

            // PV
            #pragma unroll
            for (int ks = 0; ks < 2; ++ks) {
                bf16x8 pa = *(const bf16x8*)&Pw[lm * 72 + ks * 32 + qd * 8];
                #pragma unroll
                for (int ni = 0; ni < 4; ++ni) {
                    const int d = ni * 16 + lm;
                    const int cj = kt * 8 + ks * 4 + qd;
                    const int pos = (cj & 16) | ((cj ^ (d & 15)) & 15);
                    bf16x8 bv = *(const bf16x8*)&Vs[d * 256 + pos * 8];
                    oacc[rg][ni] = __builtin_amdgcn_mfma_f32_16x16x32_bf16(
                        pa, bv, oacc[rg][ni], 0, 0, 0);
                }
            }
        }
    }

    // ---- Phase 4: rescale, transpose via LDS, coalesced stores ------------
    __syncthreads();
    u16 (*yt)[72] = (u16(*)[72])SM;     // 256x72 u16 = 36 KB
    #pragma unroll
    for (int rg = 0; rg < 2; ++rg) {
        const int trow = rg * 128 + w * 16 + qd * 4;
        #pragma unroll
        for (int r = 0; r < 4; ++r) {
            const float inv = 1.f / ls[rg][r];
            #pragma unroll
            for (int ni = 0; ni < 4; ++ni)
                yt[trow + r][ni * 16 + lm] = f2b(oacc[rg][ni][r] * inv);
        }
    }
    __syncthreads();
    #pragma unroll
    for (int rr = 0; rr < 4; ++rr) {
        const int row = rr * 64 + (tid >> 3);
        const int col = (tid & 7) * 8;
        bf16x8 vv = *(const bf16x8*)&yt[row][col];
        *(bf16x8*)(yb + ((size_t)(b * T_ + row)) * C_ + h * 64 + col) = vv;
    }
}

// ---------------------------------------------------------------------------
// Kernel 3: output projection.  yb[32768x384] @ wpb^T + bp -> fp32 out.
// 512 threads, 256x128 tile, XCD-affine, fp32 LDS-transpose epilogue.
// ---------------------------------------------------------------------------
__global__ __launch_bounds__(512, 4) void gemm_proj(
    const u16* __restrict__ yb, const u16* __restrict__ wpb,
    const float* __restrict__ bp, float* __restrict__ out)
{
    __shared__ __align__(16) u16 SMEM[256 * 64 + 128 * 64];   // 48 KB
    u16* As = SMEM;
    u16* Bs = SMEM + 256 * 64;

    const int gid  = blockIdx.x;
    const int xcd  = gid & 7;
    const int j_   = gid >> 3;            // 0..47
    const int colb = j_ % 3;
    const int rowb = (j_ / 3) * 8 + xcd;  // 0..127
    const int m0g  = rowb * 256;
    const int n0g  = colb * 128;

    const int tid = threadIdx.x;
    const int w = tid >> 6, lane = tid & 63;
    const int lm = lane & 15, qd = lane >> 4;
    const int wm = (w >> 1) * 64, wn = (w & 1) * 64;

    const int schunk = (lane & 7) ^ ((lane >> 3) & 7);
    const u16* gA = yb  + (size_t)(m0g + w * 32 + (lane >> 3)) * C_ + schunk * 8;
    const u16* gB = wpb + (size_t)(n0g + w * 16 + (lane >> 3)) * C_ + schunk * 8;
    u16* lA = &As[(w * 32) * 64];
    u16* lB = &Bs[(w * 16) * 64];

    f32x4 acc[4][4];
    #pragma unroll
    for (int mi = 0; mi < 4; ++mi)
        #pragma unroll
        for (int ni = 0; ni < 4; ++ni)
            acc[mi][ni] = (f32x4){0.f, 0.f, 0.f, 0.f};

    for (int k0 = 0; k0 < C_; k0 += 64) {
        __syncthreads();
        #pragma unroll
        for (int j = 0; j < 4; ++j)
            gl2lds16(gA + j * 8 * C_, lA + j * 8 * 64);
        #pragma unroll
        for (int j = 0; j < 2; ++j)
            gl2lds16(gB + j * 8 * C_, lB + j * 8 * 64);
        gA += 64; gB += 64;
        __syncthreads();

        #pragma unroll
        for (int ks = 0; ks < 2; ++ks) {
            bf16x8 af[4], bfr[4];
            #pragma unroll
            for (int mi = 0; mi < 4; ++mi) {
                const int row = wm + mi * 16 + lm;
                const int sl = (ks * 4 + qd) ^ (lm & 7);
                af[mi] = *(const bf16x8*)&As[row * 64 + sl * 8];
            }
            #pragma unroll
            for (int ni = 0; ni < 4; ++ni) {
                const int row = wn + ni * 16 + lm;
                const int sl = (ks * 4 + qd) ^ (lm & 7);
                bfr[ni] = *(const bf16x8*)&Bs[row * 64 + sl * 8];
            }
            #pragma unroll
            for (int mi = 0; mi < 4; ++mi)
                #pragma unroll
                for (int ni = 0; ni < 4; ++ni)
                    acc[mi][ni] = __builtin_amdgcn_mfma_f32_16x16x32_bf16(
                        af[mi], bfr[ni], acc[mi][ni], 0, 0, 0);
        }
    }

    // fp32 LDS-transpose epilogue with fused bias
    float bpv[4];
    #pragma unroll
    for (int ni = 0; ni < 4; ++ni) bpv[ni] = bp[n0g + wn + ni * 16 + lm];

    float (*tb)[132] = (float(*)[132])SMEM;   // 64x132 f32 = 33.8 KB <= 48 KB
    const int rloc = tid >> 3;                // 0..63
    #pragma unroll
    for (int mi = 0; mi < 4; ++mi) {
        __syncthreads();
        #pragma unroll
        for (int ni = 0; ni < 4; ++ni)
            #pragma unroll
            for (int r = 0; r < 4; ++r)
                tb[(w >> 1) * 16 + qd * 4 + r][wn + ni * 16 + lm]
                    = acc[mi][ni][r] + bpv[ni];
        __syncthreads();
        const int m = m0g + (rloc >> 4) * 64 + mi * 16 + (rloc & 15);
        #pragma unroll
        for (int jj = 0; jj < 4; ++jj) {
            const int cc = (tid & 7) * 4 + jj * 32;
            float4 vv = *(const float4*)&tb[rloc][cc];
            *(float4*)(out + (size_t)m * C_ + n0g + cc) = vv;
        }
    }
}

// ---------------------------------------------------------------------------
extern "C" void kernel_launch(void* const* d_in, const int* in_sizes, int n_in,
                              void* d_out, int out_size, void* d_ws, size_t ws_size,
                              hipStream_t stream)
{
    const float* x  = (const float*)d_in[0];
    const float* Wq = (const float*)d_in[1];
    const float* Wk = (const float*)d_in[2];
    const float* Wv = (const float*)d_in[3];
    const float* Wp = (const float*)d_in[4];
    const float* bp = (const float*)d_in[5];
    float* out = (float*)d_out;

    u16* xb  = (u16*)d_ws;                         // 32768*384
    u16* wct = xb  + (size_t)NTOK * C_;            // 1152*384 (head-major)
    u16* wpb = wct + (size_t)NQKV * C_;            // 384*384
    u16* yb  = wpb + (size_t)C_ * C_;              // 32768*384

    const int prep_blocks = (J0_ + J2_ + J1_ + 255) / 256;
    hipLaunchKernelGGL(prep, dim3(prep_blocks), dim3(256), 0, stream,
                       x, Wq, Wk, Wv, Wp, xb, wct, wpb);

    hipLaunchKernelGGL(qkv_attn, dim3(B_ * H_), dim3(512), 0, stream,
                       xb, wct, yb);

    hipLaunchKernelGGL(gemm_proj, dim3((NTOK / 256) * (C_ / 128)), dim3(512), 0, stream,
                       yb, wpb, bp, out);
}